// Round 11
// baseline (182.782 us; speedup 1.0000x reference)
//
#include <hip/hip_runtime.h>

// GRU decoder via MFMA, round 12: B=32768, T=48, F=16, H=32.
// = R11 (verified barrier-free lane-local recurrence, ~57us kernel) + DUAL-
// TILE ILP. R11 counters-arithmetic: ~2860 cy/step/SIMD vs ~1040 cy issue ->
// ~64% dependency stall with only 2 waves/SIMD (grid-capped: 2048 16-row
// tiles is max parallelism). Fix: each wave owns TWO independent 16-row
// tiles (grid 1024): 24 MFMAs + 16 gate elems/step across two independent
// recurrence chains -> scheduler interleaves them to fill trans/DS latency.
// Weight frags + gate consts shared across tiles (VGPR amortized); state
// (hc, hB, po, feat prefetch) duplicated. Peak ~230 VGPR < 256.
// Everything else identical to R11 (verified): permuted gate-column m-order
// hid(r,T)=(r>>2)*8+T*4+(r&3) making D-output == next-step B-frag (lane-
// local h recurrence, no LDS/barriers in loop); po via bf16 hi+lo in K
// slots 16/17 (Wk row 0); 5-trans gate form; xor16 swizzle + xor32
// bpermute dense reduce (now tree-summed, depth 4).
// Layouts (verified m89/m91/m120):
//   D[m][n]: col=lane&15=batch, row=(lane>>4)*4+reg  (m = PERMUTED gatecol)
//   A[m=lane&15][k=(lane>>4)*8+j] ; B[k=(lane>>4)*8+j][n=lane&15]

typedef __attribute__((ext_vector_type(8))) short short8;
typedef __attribute__((ext_vector_type(4))) float f32x4;

constexpr int T_STEPS  = 48;
constexpr int F_DIM    = 16;
constexpr int H_DIM    = 32;
constexpr int O_STRIDE = 17;              // obuf leading stride (floats)

union S8 { short8 s; unsigned u[4]; };

__device__ __forceinline__ unsigned pk_bf16(float hi, float lo) {
    // (bf16(hi)<<16)|bf16(lo), round-half-up
    return __builtin_amdgcn_perm(__float_as_uint(hi) + 0x8000u,
                                 __float_as_uint(lo) + 0x8000u, 0x07060302u);
}
__device__ __forceinline__ short bf16s(float x) {
    return (short)((__float_as_uint(x) + 0x8000u) >> 16);
}
__device__ __forceinline__ float rcpf(float x) { return __builtin_amdgcn_rcpf(x); }
__device__ __forceinline__ float ex2(float x)  { return __builtin_amdgcn_exp2f(x); }
#define MFMA(a, b, c) __builtin_amdgcn_mfma_f32_16x16x32_bf16(a, b, c, 0, 0, 0)
#define SWZ16(v) __int_as_float(__builtin_amdgcn_ds_swizzle(__float_as_int(v), 0x401F))
#define BPERM(a, v) __builtin_amdgcn_ds_bpermute((a), (v))

__global__ __launch_bounds__(64, 1)
void gru_mfma12(const float* __restrict__ feat,     // [B,T,F]
                const float* __restrict__ init_in,  // [B,1]
                const float* __restrict__ init_h,   // [B,H]
                const float* __restrict__ Wk,       // [17,96]
                const float* __restrict__ Rk,       // [32,96]
                const float* __restrict__ bx,       // [96]
                const float* __restrict__ bh,       // [96]
                const float* __restrict__ dw,       // [32]
                const float* __restrict__ db,       // [1]
                float* __restrict__ out)            // [B,T]
{
    __shared__ __align__(16) float obuf[2 * T_STEPS * O_STRIDE];

    const int lane = threadIdx.x;             // block = 64 = ONE wave
    const int ln   = lane & 15;               // batch col
    const int quad = lane >> 4;
    const int b0   = blockIdx.x * 32;         // tile0 rows b0.., tile1 rows b0+16..
    const int bpa  = (lane ^ 32) << 2;        // xor32 bpermute addr

    const float SZ = -1.44269504088896340736f;   // -log2(e)  (sigmoid args)
    const float SC =  2.88539008177792681472f;   // 2*log2(e) (tanh arg)

    // Permuted A-column for this lane's m-row (ln): cA(T) = (ln>>2)*8+T*4+(ln&3)
    const int cA0 = (ln >> 2) * 8 + (ln & 3);
    const int cA1 = cA0 + 4;

    // ---- A-operand weight fragments, 6 m-tiles x {W,R} (SHARED by tiles) ----
    S8 WzA, WrA, WhA, WzB, WrB, WhB, RzA, RrA, RhA, RzB, RrB, RhB;
#pragma unroll
    for (int j = 0; j < 8; ++j) {
        const int k = quad * 8 + j;
        float wzA = 0, wrA = 0, whA = 0, wzB = 0, wrB = 0, whB = 0;
        if (k < 16) {                       // feat rows 0..15 -> Wk rows 1..16
            const float* Wrow = Wk + (size_t)(k + 1) * 96;
            wzA = Wrow[cA0]; wrA = Wrow[32 + cA0]; whA = Wrow[64 + cA0];
            wzB = Wrow[cA1]; wrB = Wrow[32 + cA1]; whB = Wrow[64 + cA1];
        } else if (k < 18) {                // k=16: po_hi, k=17: po_lo (Wk row 0)
            wzA = Wk[cA0]; wrA = Wk[32 + cA0]; whA = Wk[64 + cA0];
            wzB = Wk[cA1]; wrB = Wk[32 + cA1]; whB = Wk[64 + cA1];
        }
        WzA.s[j] = bf16s(SZ * wzA); WrA.s[j] = bf16s(SZ * wrA); WhA.s[j] = bf16s(SC * whA);
        WzB.s[j] = bf16s(SZ * wzB); WrB.s[j] = bf16s(SZ * wrB); WhB.s[j] = bf16s(SC * whB);
        const float* Rrow = Rk + (size_t)k * 96;
        RzA.s[j] = bf16s(SZ * Rrow[cA0]); RrA.s[j] = bf16s(SZ * Rrow[32 + cA0]);
        RhA.s[j] = bf16s(SC * Rrow[64 + cA0]);
        RzB.s[j] = bf16s(SZ * Rrow[cA1]); RrB.s[j] = bf16s(SZ * Rrow[32 + cA1]);
        RhB.s[j] = bf16s(SC * Rrow[64 + cA1]);
    }

    // ---- per-lane D-side constants: c = quad*8 + T*4 + i (SHARED) ----
    f32x4 czA, crA, chA, cgA, czB, crB, chB, cgB, dwA, dwB;
#pragma unroll
    for (int i = 0; i < 4; ++i) {
        const int c0 = quad * 8 + i, c1 = c0 + 4;
        czA[i] = SZ * (bx[c0] + bh[c0]);           czB[i] = SZ * (bx[c1] + bh[c1]);
        crA[i] = SZ * (bx[32 + c0] + bh[32 + c0]); crB[i] = SZ * (bx[32 + c1] + bh[32 + c1]);
        chA[i] = SC * bx[64 + c0];                 chB[i] = SC * bx[64 + c1];
        cgA[i] = SC * bh[64 + c0];                 cgB[i] = SC * bh[64 + c1];
        dwA[i] = dw[c0];                           dwB[i] = dw[c1];
    }
    const float dbs = db[0];

    // ---- initial state, both tiles (lane-local, permuted layout) ----
    f32x4 hcA0, hcB0, hcA1, hcB1;
#pragma unroll
    for (int i = 0; i < 4; ++i) {
        hcA0[i] = init_h[(size_t)(b0 + ln) * H_DIM + quad * 8 + i];
        hcB0[i] = init_h[(size_t)(b0 + ln) * H_DIM + quad * 8 + 4 + i];
        hcA1[i] = init_h[(size_t)(b0 + 16 + ln) * H_DIM + quad * 8 + i];
        hcB1[i] = init_h[(size_t)(b0 + 16 + ln) * H_DIM + quad * 8 + 4 + i];
    }
    S8 hB0, hB1;
    hB0.u[0] = pk_bf16(hcA0[1], hcA0[0]); hB0.u[1] = pk_bf16(hcA0[3], hcA0[2]);
    hB0.u[2] = pk_bf16(hcB0[1], hcB0[0]); hB0.u[3] = pk_bf16(hcB0[3], hcB0[2]);
    hB1.u[0] = pk_bf16(hcA1[1], hcA1[0]); hB1.u[1] = pk_bf16(hcA1[3], hcA1[2]);
    hB1.u[2] = pk_bf16(hcB1[1], hcB1[0]); hB1.u[3] = pk_bf16(hcB1[3], hcB1[2]);

    float po0 = init_in[b0 + ln];
    float po1 = init_in[b0 + 16 + ln];

    // ---- feat prefetch, depth 2, both tiles ----
    const float* fq0 = feat + (size_t)(b0 + ln) * (T_STEPS * F_DIM) + (quad & 1) * 8;
    const float* fq1 = feat + (size_t)(b0 + 16 + ln) * (T_STEPS * F_DIM) + (quad & 1) * 8;
    f32x4 p0a0 = *(const f32x4*)(fq0);
    f32x4 p0b0 = *(const f32x4*)(fq0 + 4);
    f32x4 p0a1 = *(const f32x4*)(fq0 + F_DIM);
    f32x4 p0b1 = *(const f32x4*)(fq0 + F_DIM + 4);
    f32x4 p1a0 = *(const f32x4*)(fq1);
    f32x4 p1b0 = *(const f32x4*)(fq1 + 4);
    f32x4 p1a1 = *(const f32x4*)(fq1 + F_DIM);
    f32x4 p1b1 = *(const f32x4*)(fq1 + F_DIM + 4);

    // One step, BOTH tiles: NO barrier, NO LDS in the recurrence.
#define STEP2(T_, PA0_, PB0_, PA1_, PB1_) do {                                 \
        S8 xa0, xa1;                                                           \
        {                                                                      \
            const unsigned zm = (quad < 2) ? 0xFFFFFFFFu : 0u;                 \
            xa0.u[0] = pk_bf16(PA0_[1], PA0_[0]) & zm;                         \
            xa0.u[1] = pk_bf16(PA0_[3], PA0_[2]) & zm;                         \
            xa0.u[2] = pk_bf16(PB0_[1], PB0_[0]) & zm;                         \
            xa0.u[3] = pk_bf16(PB0_[3], PB0_[2]) & zm;                         \
            xa1.u[0] = pk_bf16(PA1_[1], PA1_[0]) & zm;                         \
            xa1.u[1] = pk_bf16(PA1_[3], PA1_[2]) & zm;                         \
            xa1.u[2] = pk_bf16(PB1_[1], PB1_[0]) & zm;                         \
            xa1.u[3] = pk_bf16(PB1_[3], PB1_[2]) & zm;                         \
            if (quad == 2) {   /* po as bf16 hi+lo in K slots 16/17 */         \
                const float ph0 = __uint_as_float(                             \
                    (__float_as_uint(po0) + 0x8000u) & 0xFFFF0000u);           \
                const float ph1 = __uint_as_float(                             \
                    (__float_as_uint(po1) + 0x8000u) & 0xFFFF0000u);           \
                xa0.u[0] = pk_bf16(po0 - ph0, ph0);                            \
                xa1.u[0] = pk_bf16(po1 - ph1, ph1);                            \
            }                                                                  \
        }                                                                      \
        {   /* prefetch feat(T_+2), both tiles */                              \
            const int t2 = ((T_) + 2 < T_STEPS) ? (T_) + 2 : T_STEPS - 1;      \
            PA0_ = *(const f32x4*)(fq0 + t2 * F_DIM);                          \
            PB0_ = *(const f32x4*)(fq0 + t2 * F_DIM + 4);                      \
            PA1_ = *(const f32x4*)(fq1 + t2 * F_DIM);                          \
            PB1_ = *(const f32x4*)(fq1 + t2 * F_DIM + 4);                      \
        }                                                                      \
        /* 24 MFMAs: 6 m-tiles x {W,R} x 2 batch tiles (independent) */        \
        f32x4 aZA0 = czA, aRA0 = crA, aHA0 = chA, aGA0 = cgA;                  \
        f32x4 aZB0 = czB, aRB0 = crB, aHB0 = chB, aGB0 = cgB;                  \
        f32x4 aZA1 = czA, aRA1 = crA, aHA1 = chA, aGA1 = cgA;                  \
        f32x4 aZB1 = czB, aRB1 = crB, aHB1 = chB, aGB1 = cgB;                  \
        aZA0 = MFMA(WzA.s, xa0.s, aZA0);  aZA1 = MFMA(WzA.s, xa1.s, aZA1);     \
        aZB0 = MFMA(WzB.s, xa0.s, aZB0);  aZB1 = MFMA(WzB.s, xa1.s, aZB1);     \
        aRA0 = MFMA(WrA.s, xa0.s, aRA0);  aRA1 = MFMA(WrA.s, xa1.s, aRA1);     \
        aRB0 = MFMA(WrB.s, xa0.s, aRB0);  aRB1 = MFMA(WrB.s, xa1.s, aRB1);     \
        aHA0 = MFMA(WhA.s, xa0.s, aHA0);  aHA1 = MFMA(WhA.s, xa1.s, aHA1);     \
        aHB0 = MFMA(WhB.s, xa0.s, aHB0);  aHB1 = MFMA(WhB.s, xa1.s, aHB1);     \
        aZA0 = MFMA(RzA.s, hB0.s, aZA0);  aZA1 = MFMA(RzA.s, hB1.s, aZA1);     \
        aZB0 = MFMA(RzB.s, hB0.s, aZB0);  aZB1 = MFMA(RzB.s, hB1.s, aZB1);     \
        aRA0 = MFMA(RrA.s, hB0.s, aRA0);  aRA1 = MFMA(RrA.s, hB1.s, aRA1);     \
        aRB0 = MFMA(RrB.s, hB0.s, aRB0);  aRB1 = MFMA(RrB.s, hB1.s, aRB1);     \
        aGA0 = MFMA(RhA.s, hB0.s, aGA0);  aGA1 = MFMA(RhA.s, hB1.s, aGA1);     \
        aGB0 = MFMA(RhB.s, hB0.s, aGB0);  aGB1 = MFMA(RhB.s, hB1.s, aGB1);     \
        /* gates: 5-trans form, 4 chains interleaved (A0,A1,B0,B1) */          \
        _Pragma("unroll")                                                      \
        for (int i = 0; i < 4; ++i) {                                          \
            {                                                                  \
                const float Ez = ex2(aZA0[i]);                                 \
                const float rr = rcpf(1.0f + ex2(aRA0[i]));                    \
                const float vv = fmaf(rr, aGA0[i], aHA0[i]);                   \
                const float Dv = 1.0f + ex2(vv);                               \
                const float num = fmaf(hcA0[i], Dv, (Dv - 2.0f) * Ez);         \
                const float den = fmaf(Dv, Ez, Dv);                            \
                hcA0[i] = num * rcpf(den);                                     \
            }                                                                  \
            {                                                                  \
                const float Ez = ex2(aZA1[i]);                                 \
                const float rr = rcpf(1.0f + ex2(aRA1[i]));                    \
                const float vv = fmaf(rr, aGA1[i], aHA1[i]);                   \
                const float Dv = 1.0f + ex2(vv);                               \
                const float num = fmaf(hcA1[i], Dv, (Dv - 2.0f) * Ez);         \
                const float den = fmaf(Dv, Ez, Dv);                            \
                hcA1[i] = num * rcpf(den);                                     \
            }                                                                  \
            {                                                                  \
                const float Ez = ex2(aZB0[i]);                                 \
                const float rr = rcpf(1.0f + ex2(aRB0[i]));                    \
                const float vv = fmaf(rr, aGB0[i], aHB0[i]);                   \
                const float Dv = 1.0f + ex2(vv);                               \
                const float num = fmaf(hcB0[i], Dv, (Dv - 2.0f) * Ez);         \
                const float den = fmaf(Dv, Ez, Dv);                            \
                hcB0[i] = num * rcpf(den);                                     \
            }                                                                  \
            {                                                                  \
                const float Ez = ex2(aZB1[i]);                                 \
                const float rr = rcpf(1.0f + ex2(aRB1[i]));                    \
                const float vv = fmaf(rr, aGB1[i], aHB1[i]);                   \
                const float Dv = 1.0f + ex2(vv);                               \
                const float num = fmaf(hcB1[i], Dv, (Dv - 2.0f) * Ez);         \
                const float den = fmaf(Dv, Ez, Dv);                            \
                hcB1[i] = num * rcpf(den);                                     \
            }                                                                  \
        }                                                                      \
        /* repack B-frags for next step (lane-local) */                        \
        hB0.u[0] = pk_bf16(hcA0[1], hcA0[0]);                                  \
        hB0.u[1] = pk_bf16(hcA0[3], hcA0[2]);                                  \
        hB0.u[2] = pk_bf16(hcB0[1], hcB0[0]);                                  \
        hB0.u[3] = pk_bf16(hcB0[3], hcB0[2]);                                  \
        hB1.u[0] = pk_bf16(hcA1[1], hcA1[0]);                                  \
        hB1.u[1] = pk_bf16(hcA1[3], hcA1[2]);                                  \
        hB1.u[2] = pk_bf16(hcB1[1], hcB1[0]);                                  \
        hB1.u[3] = pk_bf16(hcB1[3], hcB1[2]);                                  \
        /* dense: tree sum of own 8 units, then xor16+xor32 reduce */          \
        float s0 = fmaf(hcA0[0], dwA[0], hcA0[1] * dwA[1])                     \
                 + fmaf(hcA0[2], dwA[2], hcA0[3] * dwA[3]);                    \
        float u0 = fmaf(hcB0[0], dwB[0], hcB0[1] * dwB[1])                     \
                 + fmaf(hcB0[2], dwB[2], hcB0[3] * dwB[3]);                    \
        float s1 = fmaf(hcA1[0], dwA[0], hcA1[1] * dwA[1])                     \
                 + fmaf(hcA1[2], dwA[2], hcA1[3] * dwA[3]);                    \
        float u1 = fmaf(hcB1[0], dwB[0], hcB1[1] * dwB[1])                     \
                 + fmaf(hcB1[2], dwB[2], hcB1[3] * dwB[3]);                    \
        s0 += u0; s1 += u1;                                                    \
        s0 += SWZ16(s0); s1 += SWZ16(s1);                                      \
        s0 += __int_as_float(BPERM(bpa, __float_as_int(s0)));                  \
        s1 += __int_as_float(BPERM(bpa, __float_as_int(s1)));                  \
        po0 = s0 + dbs; po1 = s1 + dbs;                                        \
        if (lane < 16) {                                                       \
            obuf[(T_) * O_STRIDE + lane] = po0;                                \
            obuf[T_STEPS * O_STRIDE + (T_) * O_STRIDE + lane] = po1;           \
        }                                                                      \
    } while (0)

    for (int t = 0; t < T_STEPS; t += 2) {
        STEP2(t,     p0a0, p0b0, p1a0, p1b0);
        STEP2(t + 1, p0a1, p0b1, p1a1, p1b1);
    }
#undef STEP2

    // ---- flush outputs (single wave, both tiles): coalesced dwordx4 ----
    __builtin_amdgcn_s_waitcnt(0xC07F);            // drain obuf ds_writes
    {
        const int row = lane >> 2;                 // 0..15
        const int tb  = (lane & 3) * 12;           // 0,12,24,36
#pragma unroll
        for (int tile = 0; tile < 2; ++tile) {
            const float* ob = obuf + tile * (T_STEPS * O_STRIDE);
            float* orow = out + (size_t)(b0 + tile * 16 + row) * T_STEPS + tb;
#pragma unroll
            for (int k = 0; k < 3; ++k) {
                f32x4 v;
#pragma unroll
                for (int e = 0; e < 4; ++e) v[e] = ob[(tb + k * 4 + e) * O_STRIDE + row];
                *(f32x4*)(orow + k * 4) = v;
            }
        }
    }
}

extern "C" void kernel_launch(void* const* d_in, const int* in_sizes, int n_in,
                              void* d_out, int out_size, void* d_ws, size_t ws_size,
                              hipStream_t stream) {
    const float* feat    = (const float*)d_in[0];
    const float* init_in = (const float*)d_in[1];
    const float* init_h  = (const float*)d_in[2];
    const float* Wk      = (const float*)d_in[3];
    const float* Rk      = (const float*)d_in[4];
    const float* bx      = (const float*)d_in[5];
    const float* bh      = (const float*)d_in[6];
    const float* dw      = (const float*)d_in[7];
    const float* db      = (const float*)d_in[8];
    float* out           = (float*)d_out;

    const int B = in_sizes[2] / H_DIM;      // 32768
    dim3 grid((unsigned)(B / 32));          // one 1-wave block per 32 batch rows
    dim3 block(64);
    hipLaunchKernelGGL(gru_mfma12, grid, block, 0, stream,
                       feat, init_in, init_h, Wk, Rk, bx, bh, dw, db, out);
}

// Round 13
// 177.828 us; speedup vs baseline: 1.0279x; 1.0279x over previous
//
#include <hip/hip_runtime.h>

// GRU decoder via MFMA, round 13: B=32768, T=48, F=16, H=32.
// = R11 (verified best: barrier-free lane-local recurrence, ~57us, W=2048
// waves) + RANK-1 PO-FOLD. R12 falsified dual-tile ILP (67.5us, 1 wave/SIMD
// exposes chain). R11 residual chain: ...gates -> dense dot -> ds_swizzle ->
// ds_bpermute -> po -> next xa. po(t) = h(t)*dw + db is LINEAR in h ->
// its gate contribution po*w0 is the rank-1 update h*(dw (x) w0):
//   z,r gates (symmetric x+h): fold into recurrent kernel
//       R'z = Rz + dw (x) w0z, R'r = Rr + dw (x) w0r  (f32 sum, one bf16 rnd)
//   hh gate (asymmetric: tanh(xh + r*hh_in), po*w0h is x-side, NOT *r):
//       2 extra MFMAs Dwh = dw (x) w0h accumulated into x-side aH.
//   db*w0 -> folded into biases (cz, cr, ch).
// Step 0 exception (prev_out(0)=init_in != h*dw+db): prologue reduce
// delta = init_in - (h_init*dw + db), injected via K slots 16/17 (hi+lo,
// w0 rows kept in W-frags) for step 0 only, then pv=0.
// => recurrence chain: hB -> {R'z,R'r,Rh,Dwh} MFMAs -> gates -> repack hB.
// The dense reduce (swz16+bperm+obuf) is now OFF the chain entirely.
// 14 MFMAs/step. Grid 2048 x 64thr (1-wave blocks, 2 waves/SIMD = R11 shape).
// 5-trans gates unchanged. Layouts (verified m89/m91/m120):
//   D[m][n]: col=lane&15=batch, row=(lane>>4)*4+reg  (m = PERMUTED gatecol
//   hid(r,T)=(r>>2)*8+T*4+(r&3) -> D-output == next-step B-frag, lane-local)
//   A[m=lane&15][k=(lane>>4)*8+j] ; B[k=(lane>>4)*8+j][n=lane&15]

typedef __attribute__((ext_vector_type(8))) short short8;
typedef __attribute__((ext_vector_type(4))) float f32x4;

constexpr int T_STEPS  = 48;
constexpr int F_DIM    = 16;
constexpr int H_DIM    = 32;
constexpr int O_STRIDE = 17;              // obuf leading stride (floats)

union S8 { short8 s; unsigned u[4]; };

__device__ __forceinline__ unsigned pk_bf16(float hi, float lo) {
    // (bf16(hi)<<16)|bf16(lo), round-half-up
    return __builtin_amdgcn_perm(__float_as_uint(hi) + 0x8000u,
                                 __float_as_uint(lo) + 0x8000u, 0x07060302u);
}
__device__ __forceinline__ short bf16s(float x) {
    return (short)((__float_as_uint(x) + 0x8000u) >> 16);
}
__device__ __forceinline__ float rcpf(float x) { return __builtin_amdgcn_rcpf(x); }
__device__ __forceinline__ float ex2(float x)  { return __builtin_amdgcn_exp2f(x); }
#define MFMA(a, b, c) __builtin_amdgcn_mfma_f32_16x16x32_bf16(a, b, c, 0, 0, 0)
#define SWZ16(v) __int_as_float(__builtin_amdgcn_ds_swizzle(__float_as_int(v), 0x401F))
#define BPERM(a, v) __builtin_amdgcn_ds_bpermute((a), (v))

__global__ __launch_bounds__(64, 2)
void gru_mfma13(const float* __restrict__ feat,     // [B,T,F]
                const float* __restrict__ init_in,  // [B,1]
                const float* __restrict__ init_h,   // [B,H]
                const float* __restrict__ Wk,       // [17,96]
                const float* __restrict__ Rk,       // [32,96]
                const float* __restrict__ bx,       // [96]
                const float* __restrict__ bh,       // [96]
                const float* __restrict__ dw,       // [32]
                const float* __restrict__ db,       // [1]
                float* __restrict__ out)            // [B,T]
{
    __shared__ __align__(16) float obuf[T_STEPS * O_STRIDE];

    const int lane = threadIdx.x;             // block = 64 = ONE wave
    const int ln   = lane & 15;               // batch col
    const int quad = lane >> 4;
    const int b0   = blockIdx.x * 16;
    const int bpa  = (lane ^ 32) << 2;        // xor32 bpermute addr

    const float SZ = -1.44269504088896340736f;   // -log2(e)  (sigmoid args)
    const float SC =  2.88539008177792681472f;   // 2*log2(e) (tanh arg)

    // Permuted A-column for this lane's m-row (ln): cA(T) = (ln>>2)*8+T*4+(ln&3)
    const int cA0 = (ln >> 2) * 8 + (ln & 3);
    const int cA1 = cA0 + 4;

    // ---- A-operand weight fragments ----
    // W-frags: feat rows k=0..15 (Wk rows 1..16); k=16/17 = w0 (Wk row 0)
    //          for the step-0 delta injection.
    // R'-frags (z,r): Rk + dw (x) w0 rank-1 fold (f32 sum, single bf16 round).
    // Rh-frag: unchanged. Dwh-frag: dw (x) w0h (x-side hh contribution).
    S8 WzA, WrA, WhA, WzB, WrB, WhB, RzA, RrA, RhA, RzB, RrB, RhB, DwhA, DwhB;
#pragma unroll
    for (int j = 0; j < 8; ++j) {
        const int k = quad * 8 + j;
        float wzA = 0, wrA = 0, whA = 0, wzB = 0, wrB = 0, whB = 0;
        if (k < 16) {                       // feat rows 0..15 -> Wk rows 1..16
            const float* Wrow = Wk + (size_t)(k + 1) * 96;
            wzA = Wrow[cA0]; wrA = Wrow[32 + cA0]; whA = Wrow[64 + cA0];
            wzB = Wrow[cA1]; wrB = Wrow[32 + cA1]; whB = Wrow[64 + cA1];
        } else if (k < 18) {                // k=16: delta_hi, k=17: delta_lo
            wzA = Wk[cA0]; wrA = Wk[32 + cA0]; whA = Wk[64 + cA0];
            wzB = Wk[cA1]; wrB = Wk[32 + cA1]; whB = Wk[64 + cA1];
        }
        WzA.s[j] = bf16s(SZ * wzA); WrA.s[j] = bf16s(SZ * wrA); WhA.s[j] = bf16s(SC * whA);
        WzB.s[j] = bf16s(SZ * wzB); WrB.s[j] = bf16s(SZ * wrB); WhB.s[j] = bf16s(SC * whB);
        const float* Rrow = Rk + (size_t)k * 96;
        const float dwk = dw[k];
        RzA.s[j]  = bf16s(SZ * (Rrow[cA0]      + dwk * Wk[cA0]));
        RrA.s[j]  = bf16s(SZ * (Rrow[32 + cA0] + dwk * Wk[32 + cA0]));
        RhA.s[j]  = bf16s(SC * Rrow[64 + cA0]);
        DwhA.s[j] = bf16s(SC * dwk * Wk[64 + cA0]);
        RzB.s[j]  = bf16s(SZ * (Rrow[cA1]      + dwk * Wk[cA1]));
        RrB.s[j]  = bf16s(SZ * (Rrow[32 + cA1] + dwk * Wk[32 + cA1]));
        RhB.s[j]  = bf16s(SC * Rrow[64 + cA1]);
        DwhB.s[j] = bf16s(SC * dwk * Wk[64 + cA1]);
    }

    // ---- per-lane D-side constants: c = quad*8 + T*4 + i ----
    // Biases include the folded db*w0 terms (z,r sigmoid-side; h x-side).
    const float dbs = db[0];
    f32x4 czA, crA, chA, cgA, czB, crB, chB, cgB, dwA, dwB;
#pragma unroll
    for (int i = 0; i < 4; ++i) {
        const int c0 = quad * 8 + i, c1 = c0 + 4;
        czA[i] = SZ * (bx[c0] + bh[c0] + dbs * Wk[c0]);
        czB[i] = SZ * (bx[c1] + bh[c1] + dbs * Wk[c1]);
        crA[i] = SZ * (bx[32 + c0] + bh[32 + c0] + dbs * Wk[32 + c0]);
        crB[i] = SZ * (bx[32 + c1] + bh[32 + c1] + dbs * Wk[32 + c1]);
        chA[i] = SC * (bx[64 + c0] + dbs * Wk[64 + c0]);
        chB[i] = SC * (bx[64 + c1] + dbs * Wk[64 + c1]);
        cgA[i] = SC * bh[64 + c0];
        cgB[i] = SC * bh[64 + c1];
        dwA[i] = dw[c0];
        dwB[i] = dw[c1];
    }

    // ---- initial state (lane-local, permuted layout) ----
    f32x4 hcA, hcB;
#pragma unroll
    for (int i = 0; i < 4; ++i) {
        hcA[i] = init_h[(size_t)(b0 + ln) * H_DIM + quad * 8 + i];
        hcB[i] = init_h[(size_t)(b0 + ln) * H_DIM + quad * 8 + 4 + i];
    }
    S8 hB;                                     // B-frag: k=q*8+j natural order
    hB.u[0] = pk_bf16(hcA[1], hcA[0]);
    hB.u[1] = pk_bf16(hcA[3], hcA[2]);
    hB.u[2] = pk_bf16(hcB[1], hcB[0]);
    hB.u[3] = pk_bf16(hcB[3], hcB[2]);

    // ---- step-0 delta: init_in - (h_init.dw + db)  (prologue, off-chain) ----
    float pv;
    {
        float d = fmaf(hcA[0], dwA[0], hcA[1] * dwA[1])
                + fmaf(hcA[2], dwA[2], hcA[3] * dwA[3]);
        d += fmaf(hcB[0], dwB[0], hcB[1] * dwB[1])
           + fmaf(hcB[2], dwB[2], hcB[3] * dwB[3]);
        d += SWZ16(d);
        d += __int_as_float(BPERM(bpa, __float_as_int(d)));
        pv = init_in[b0 + ln] - (d + dbs);     // injected at step 0 only
    }

    // ---- feat prefetch, depth 2 ----
    const float* fqb = feat + (size_t)(b0 + ln) * (T_STEPS * F_DIM) + (quad & 1) * 8;
    f32x4 pa0 = *(const f32x4*)(fqb);
    f32x4 pb0 = *(const f32x4*)(fqb + 4);
    f32x4 pa1 = *(const f32x4*)(fqb + F_DIM);
    f32x4 pb1 = *(const f32x4*)(fqb + F_DIM + 4);

    // One step: NO barrier, NO LDS, NO cross-lane op in the recurrence.
#define GRU_STEP(T_, PA_, PB_) do {                                            \
        S8 xa;                                                                 \
        {                                                                      \
            const unsigned zm = (quad < 2) ? 0xFFFFFFFFu : 0u;                 \
            xa.u[0] = pk_bf16(PA_[1], PA_[0]) & zm;                            \
            xa.u[1] = pk_bf16(PA_[3], PA_[2]) & zm;                            \
            xa.u[2] = pk_bf16(PB_[1], PB_[0]) & zm;                            \
            xa.u[3] = pk_bf16(PB_[3], PB_[2]) & zm;                            \
            if (quad == 2) {   /* delta (step 0) as bf16 hi+lo, K 16/17 */     \
                const float ph = __uint_as_float(                              \
                    (__float_as_uint(pv) + 0x8000u) & 0xFFFF0000u);            \
                xa.u[0] = pk_bf16(pv - ph, ph);                                \
            }                                                                  \
        }                                                                      \
        {   /* prefetch feat(T_+2) */                                          \
            const int t2 = ((T_) + 2 < T_STEPS) ? (T_) + 2 : T_STEPS - 1;      \
            PA_ = *(const f32x4*)(fqb + t2 * F_DIM);                           \
            PB_ = *(const f32x4*)(fqb + t2 * F_DIM + 4);                       \
        }                                                                      \
        /* 14 MFMAs: {Wz,Wr,Wh}x{A,B} on xa; {R'z,R'r,Rh,Dwh}x{A,B} on hB */   \
        f32x4 aZA = czA, aRA = crA, aHA = chA, aGA = cgA;                      \
        f32x4 aZB = czB, aRB = crB, aHB = chB, aGB = cgB;                      \
        aZA = MFMA(WzA.s, xa.s, aZA);   aZB = MFMA(WzB.s, xa.s, aZB);          \
        aRA = MFMA(WrA.s, xa.s, aRA);   aRB = MFMA(WrB.s, xa.s, aRB);          \
        aHA = MFMA(WhA.s, xa.s, aHA);   aHB = MFMA(WhB.s, xa.s, aHB);          \
        aZA = MFMA(RzA.s, hB.s, aZA);   aZB = MFMA(RzB.s, hB.s, aZB);          \
        aRA = MFMA(RrA.s, hB.s, aRA);   aRB = MFMA(RrB.s, hB.s, aRB);          \
        aHA = MFMA(DwhA.s, hB.s, aHA);  aHB = MFMA(DwhB.s, hB.s, aHB);         \
        aGA = MFMA(RhA.s, hB.s, aGA);   aGB = MFMA(RhB.s, hB.s, aGB);          \
        /* gates: 5-trans form, NO po terms (folded into R'/biases) */         \
        _Pragma("unroll")                                                      \
        for (int i = 0; i < 4; ++i) {                                          \
            {                                                                  \
                const float Ez = ex2(aZA[i]);                                  \
                const float rr = rcpf(1.0f + ex2(aRA[i]));                     \
                const float vv = fmaf(rr, aGA[i], aHA[i]);                     \
                const float Dv = 1.0f + ex2(vv);                               \
                const float num = fmaf(hcA[i], Dv, (Dv - 2.0f) * Ez);          \
                const float den = fmaf(Dv, Ez, Dv);                            \
                hcA[i] = num * rcpf(den);                                      \
            }                                                                  \
            {                                                                  \
                const float Ez = ex2(aZB[i]);                                  \
                const float rr = rcpf(1.0f + ex2(aRB[i]));                     \
                const float vv = fmaf(rr, aGB[i], aHB[i]);                     \
                const float Dv = 1.0f + ex2(vv);                               \
                const float num = fmaf(hcB[i], Dv, (Dv - 2.0f) * Ez);          \
                const float den = fmaf(Dv, Ez, Dv);                            \
                hcB[i] = num * rcpf(den);                                      \
            }                                                                  \
        }                                                                      \
        /* repack B-frag for next step (lane-local; THE recurrence chain) */   \
        hB.u[0] = pk_bf16(hcA[1], hcA[0]);                                     \
        hB.u[1] = pk_bf16(hcA[3], hcA[2]);                                     \
        hB.u[2] = pk_bf16(hcB[1], hcB[0]);                                     \
        hB.u[3] = pk_bf16(hcB[3], hcB[2]);                                     \
        /* dense output (OFF-chain: feeds nothing in the recurrence) */        \
        float s = fmaf(hcA[0], dwA[0], hcA[1] * dwA[1])                        \
                + fmaf(hcA[2], dwA[2], hcA[3] * dwA[3]);                       \
        s += fmaf(hcB[0], dwB[0], hcB[1] * dwB[1])                             \
           + fmaf(hcB[2], dwB[2], hcB[3] * dwB[3]);                            \
        s += SWZ16(s);                                                         \
        s += __int_as_float(BPERM(bpa, __float_as_int(s)));                    \
        if (lane < 16) obuf[(T_) * O_STRIDE + lane] = s + dbs;                 \
        pv = 0.0f;   /* delta only applies at step 0 */                        \
    } while (0)

    for (int t = 0; t < T_STEPS; t += 2) {
        GRU_STEP(t,     pa0, pb0);
        GRU_STEP(t + 1, pa1, pb1);
    }
#undef GRU_STEP

    // ---- flush outputs (single wave): coalesced dwordx4 ----
    __builtin_amdgcn_s_waitcnt(0xC07F);            // drain obuf ds_writes
    {
        const int row = lane >> 2;                 // 0..15
        const int tb  = (lane & 3) * 12;           // 0,12,24,36
        float* orow = out + (size_t)(b0 + row) * T_STEPS + tb;
#pragma unroll
        for (int k = 0; k < 3; ++k) {
            f32x4 v;
#pragma unroll
            for (int e = 0; e < 4; ++e) v[e] = obuf[(tb + k * 4 + e) * O_STRIDE + row];
            *(f32x4*)(orow + k * 4) = v;
        }
    }
}

extern "C" void kernel_launch(void* const* d_in, const int* in_sizes, int n_in,
                              void* d_out, int out_size, void* d_ws, size_t ws_size,
                              hipStream_t stream) {
    const float* feat    = (const float*)d_in[0];
    const float* init_in = (const float*)d_in[1];
    const float* init_h  = (const float*)d_in[2];
    const float* Wk      = (const float*)d_in[3];
    const float* Rk      = (const float*)d_in[4];
    const float* bx      = (const float*)d_in[5];
    const float* bh      = (const float*)d_in[6];
    const float* dw      = (const float*)d_in[7];
    const float* db      = (const float*)d_in[8];
    float* out           = (float*)d_out;

    const int B = in_sizes[2] / H_DIM;      // 32768
    dim3 grid((unsigned)(B / 16));          // one 1-wave block per 16 batch rows
    dim3 block(64);
    hipLaunchKernelGGL(gru_mfma13, grid, block, 0, stream,
                       feat, init_in, init_h, Wk, Rk, bx, bh, dw, db, out);
}

// Round 14
// 176.695 us; speedup vs baseline: 1.0344x; 1.0064x over previous
//
#include <hip/hip_runtime.h>

// GRU decoder via MFMA, round 14: B=32768, T=48, F=16, H=32.
// = R13 (verified: rank-1 po-fold, barrier-free lane-local recurrence,
// 59.1us, absmax 0.0078125) + STAGE-WISE GATES. R13 counters: 2950 cy/step,
// VALUBusy 51% -> ~1500 cy issue + ~1450 cy stall per step. Stall ~= 8x a
// single element's 5-trans dependency chain (~130 cy) => hypothesis: the
// unrolled per-element gate loop is emitted element-by-element, serializing
// 8 independent trans chains. Fix: SoA restructure -- 9 stages, each stage
// = 8 independent ops (all ex2(az), all ex2(ar), all rcp, ...) so trans
// LATENCY is hidden by the 7 sibling elements; chain -> issue-bound.
// Per-element math BIT-IDENTICAL to R13 (only program-order interleave
// changes) -> absmax must stay 0.0078125.
// Structure (R13, verified): permuted gate-column m-order
// hid(r,T)=(r>>2)*8+T*4+(r&3) -> D-output == next-step B-frag (lane-local
// recurrence, no LDS/barrier/cross-lane in the chain); rank-1 po-fold
// R'z=Rz+dw(x)w0z, R'r=Rr+dw(x)w0r, x-side Dwh=dw(x)w0h (2 extra MFMAs),
// db*w0 in biases; step-0 delta via K slots 16/17. 14 MFMAs/step.
// Grid 2048 x 64thr (1-wave blocks, 2 waves/SIMD).
// Layouts (verified m89/m91/m120):
//   D[m][n]: col=lane&15=batch, row=(lane>>4)*4+reg  (m = PERMUTED gatecol)
//   A[m=lane&15][k=(lane>>4)*8+j] ; B[k=(lane>>4)*8+j][n=lane&15]

typedef __attribute__((ext_vector_type(8))) short short8;
typedef __attribute__((ext_vector_type(4))) float f32x4;

constexpr int T_STEPS  = 48;
constexpr int F_DIM    = 16;
constexpr int H_DIM    = 32;
constexpr int O_STRIDE = 17;              // obuf leading stride (floats)

union S8 { short8 s; unsigned u[4]; };

__device__ __forceinline__ unsigned pk_bf16(float hi, float lo) {
    // (bf16(hi)<<16)|bf16(lo), round-half-up
    return __builtin_amdgcn_perm(__float_as_uint(hi) + 0x8000u,
                                 __float_as_uint(lo) + 0x8000u, 0x07060302u);
}
__device__ __forceinline__ short bf16s(float x) {
    return (short)((__float_as_uint(x) + 0x8000u) >> 16);
}
__device__ __forceinline__ float rcpf(float x) { return __builtin_amdgcn_rcpf(x); }
__device__ __forceinline__ float ex2(float x)  { return __builtin_amdgcn_exp2f(x); }
#define MFMA(a, b, c) __builtin_amdgcn_mfma_f32_16x16x32_bf16(a, b, c, 0, 0, 0)
#define SWZ16(v) __int_as_float(__builtin_amdgcn_ds_swizzle(__float_as_int(v), 0x401F))
#define BPERM(a, v) __builtin_amdgcn_ds_bpermute((a), (v))

__global__ __launch_bounds__(64, 2)
void gru_mfma14(const float* __restrict__ feat,     // [B,T,F]
                const float* __restrict__ init_in,  // [B,1]
                const float* __restrict__ init_h,   // [B,H]
                const float* __restrict__ Wk,       // [17,96]
                const float* __restrict__ Rk,       // [32,96]
                const float* __restrict__ bx,       // [96]
                const float* __restrict__ bh,       // [96]
                const float* __restrict__ dw,       // [32]
                const float* __restrict__ db,       // [1]
                float* __restrict__ out)            // [B,T]
{
    __shared__ __align__(16) float obuf[T_STEPS * O_STRIDE];

    const int lane = threadIdx.x;             // block = 64 = ONE wave
    const int ln   = lane & 15;               // batch col
    const int quad = lane >> 4;
    const int b0   = blockIdx.x * 16;
    const int bpa  = (lane ^ 32) << 2;        // xor32 bpermute addr

    const float SZ = -1.44269504088896340736f;   // -log2(e)  (sigmoid args)
    const float SC =  2.88539008177792681472f;   // 2*log2(e) (tanh arg)

    // Permuted A-column for this lane's m-row (ln): cA(T) = (ln>>2)*8+T*4+(ln&3)
    const int cA0 = (ln >> 2) * 8 + (ln & 3);
    const int cA1 = cA0 + 4;

    // ---- A-operand weight fragments (R13 layout, verified) ----
    S8 WzA, WrA, WhA, WzB, WrB, WhB, RzA, RrA, RhA, RzB, RrB, RhB, DwhA, DwhB;
#pragma unroll
    for (int j = 0; j < 8; ++j) {
        const int k = quad * 8 + j;
        float wzA = 0, wrA = 0, whA = 0, wzB = 0, wrB = 0, whB = 0;
        if (k < 16) {                       // feat rows 0..15 -> Wk rows 1..16
            const float* Wrow = Wk + (size_t)(k + 1) * 96;
            wzA = Wrow[cA0]; wrA = Wrow[32 + cA0]; whA = Wrow[64 + cA0];
            wzB = Wrow[cA1]; wrB = Wrow[32 + cA1]; whB = Wrow[64 + cA1];
        } else if (k < 18) {                // k=16: delta_hi, k=17: delta_lo
            wzA = Wk[cA0]; wrA = Wk[32 + cA0]; whA = Wk[64 + cA0];
            wzB = Wk[cA1]; wrB = Wk[32 + cA1]; whB = Wk[64 + cA1];
        }
        WzA.s[j] = bf16s(SZ * wzA); WrA.s[j] = bf16s(SZ * wrA); WhA.s[j] = bf16s(SC * whA);
        WzB.s[j] = bf16s(SZ * wzB); WrB.s[j] = bf16s(SZ * wrB); WhB.s[j] = bf16s(SC * whB);
        const float* Rrow = Rk + (size_t)k * 96;
        const float dwk = dw[k];
        RzA.s[j]  = bf16s(SZ * (Rrow[cA0]      + dwk * Wk[cA0]));
        RrA.s[j]  = bf16s(SZ * (Rrow[32 + cA0] + dwk * Wk[32 + cA0]));
        RhA.s[j]  = bf16s(SC * Rrow[64 + cA0]);
        DwhA.s[j] = bf16s(SC * dwk * Wk[64 + cA0]);
        RzB.s[j]  = bf16s(SZ * (Rrow[cA1]      + dwk * Wk[cA1]));
        RrB.s[j]  = bf16s(SZ * (Rrow[32 + cA1] + dwk * Wk[32 + cA1]));
        RhB.s[j]  = bf16s(SC * Rrow[64 + cA1]);
        DwhB.s[j] = bf16s(SC * dwk * Wk[64 + cA1]);
    }

    // ---- per-lane D-side constants: c = quad*8 + T*4 + i (R13, verified) ----
    const float dbs = db[0];
    f32x4 czA, crA, chA, cgA, czB, crB, chB, cgB, dwA, dwB;
#pragma unroll
    for (int i = 0; i < 4; ++i) {
        const int c0 = quad * 8 + i, c1 = c0 + 4;
        czA[i] = SZ * (bx[c0] + bh[c0] + dbs * Wk[c0]);
        czB[i] = SZ * (bx[c1] + bh[c1] + dbs * Wk[c1]);
        crA[i] = SZ * (bx[32 + c0] + bh[32 + c0] + dbs * Wk[32 + c0]);
        crB[i] = SZ * (bx[32 + c1] + bh[32 + c1] + dbs * Wk[32 + c1]);
        chA[i] = SC * (bx[64 + c0] + dbs * Wk[64 + c0]);
        chB[i] = SC * (bx[64 + c1] + dbs * Wk[64 + c1]);
        cgA[i] = SC * bh[64 + c0];
        cgB[i] = SC * bh[64 + c1];
        dwA[i] = dw[c0];
        dwB[i] = dw[c1];
    }

    // ---- initial state (lane-local, permuted layout) ----
    float hc[8];
#pragma unroll
    for (int i = 0; i < 4; ++i) {
        hc[i]     = init_h[(size_t)(b0 + ln) * H_DIM + quad * 8 + i];
        hc[i + 4] = init_h[(size_t)(b0 + ln) * H_DIM + quad * 8 + 4 + i];
    }
    S8 hB;                                     // B-frag: k=q*8+j natural order
    hB.u[0] = pk_bf16(hc[1], hc[0]);
    hB.u[1] = pk_bf16(hc[3], hc[2]);
    hB.u[2] = pk_bf16(hc[5], hc[4]);
    hB.u[3] = pk_bf16(hc[7], hc[6]);

    // ---- step-0 delta: init_in - (h_init.dw + db)  (prologue, off-chain) ----
    float pv;
    {
        float d = fmaf(hc[0], dwA[0], hc[1] * dwA[1])
                + fmaf(hc[2], dwA[2], hc[3] * dwA[3]);
        d += fmaf(hc[4], dwB[0], hc[5] * dwB[1])
           + fmaf(hc[6], dwB[2], hc[7] * dwB[3]);
        d += SWZ16(d);
        d += __int_as_float(BPERM(bpa, __float_as_int(d)));
        pv = init_in[b0 + ln] - (d + dbs);     // injected at step 0 only
    }

    // ---- feat prefetch, depth 2 ----
    const float* fqb = feat + (size_t)(b0 + ln) * (T_STEPS * F_DIM) + (quad & 1) * 8;
    f32x4 pa0 = *(const f32x4*)(fqb);
    f32x4 pb0 = *(const f32x4*)(fqb + 4);
    f32x4 pa1 = *(const f32x4*)(fqb + F_DIM);
    f32x4 pb1 = *(const f32x4*)(fqb + F_DIM + 4);

    // One step: NO barrier, NO LDS, NO cross-lane op in the recurrence.
    // Gates computed STAGE-WISE over all 8 elements (SoA) so each trans
    // op's latency is hidden by the 7 independent siblings.
#define GRU_STEP(T_, PA_, PB_) do {                                            \
        S8 xa;                                                                 \
        {                                                                      \
            const unsigned zm = (quad < 2) ? 0xFFFFFFFFu : 0u;                 \
            xa.u[0] = pk_bf16(PA_[1], PA_[0]) & zm;                            \
            xa.u[1] = pk_bf16(PA_[3], PA_[2]) & zm;                            \
            xa.u[2] = pk_bf16(PB_[1], PB_[0]) & zm;                            \
            xa.u[3] = pk_bf16(PB_[3], PB_[2]) & zm;                            \
            if (quad == 2) {   /* delta (step 0) as bf16 hi+lo, K 16/17 */     \
                const float ph = __uint_as_float(                              \
                    (__float_as_uint(pv) + 0x8000u) & 0xFFFF0000u);            \
                xa.u[0] = pk_bf16(pv - ph, ph);                                \
            }                                                                  \
        }                                                                      \
        {   /* prefetch feat(T_+2) */                                          \
            const int t2 = ((T_) + 2 < T_STEPS) ? (T_) + 2 : T_STEPS - 1;      \
            PA_ = *(const f32x4*)(fqb + t2 * F_DIM);                           \
            PB_ = *(const f32x4*)(fqb + t2 * F_DIM + 4);                       \
        }                                                                      \
        /* 14 MFMAs: {Wz,Wr,Wh}x{A,B} on xa; {R'z,R'r,Rh,Dwh}x{A,B} on hB */   \
        f32x4 aZA = czA, aRA = crA, aHA = chA, aGA = cgA;                      \
        f32x4 aZB = czB, aRB = crB, aHB = chB, aGB = cgB;                      \
        aZA = MFMA(WzA.s, xa.s, aZA);   aZB = MFMA(WzB.s, xa.s, aZB);          \
        aRA = MFMA(WrA.s, xa.s, aRA);   aRB = MFMA(WrB.s, xa.s, aRB);          \
        aHA = MFMA(WhA.s, xa.s, aHA);   aHB = MFMA(WhB.s, xa.s, aHB);          \
        aZA = MFMA(RzA.s, hB.s, aZA);   aZB = MFMA(RzB.s, hB.s, aZB);          \
        aRA = MFMA(RrA.s, hB.s, aRA);   aRB = MFMA(RrB.s, hB.s, aRB);          \
        aHA = MFMA(DwhA.s, hB.s, aHA);  aHB = MFMA(DwhB.s, hB.s, aHB);         \
        aGA = MFMA(RhA.s, hB.s, aGA);   aGB = MFMA(RhB.s, hB.s, aGB);          \
        /* ---- stage-wise gates (SoA; per-element math == R13) ---- */        \
        float az[8], ar[8], ah[8], ag[8];                                      \
        _Pragma("unroll")                                                      \
        for (int i = 0; i < 4; ++i) {                                          \
            az[i] = aZA[i]; az[i + 4] = aZB[i];                                \
            ar[i] = aRA[i]; ar[i + 4] = aRB[i];                                \
            ah[i] = aHA[i]; ah[i + 4] = aHB[i];                                \
            ag[i] = aGA[i]; ag[i + 4] = aGB[i];                                \
        }                                                                      \
        float Ez[8], tr[8], rr[8], vv[8], Dv[8], num[8], den[8], rd[8];        \
        _Pragma("unroll")                                                      \
        for (int e = 0; e < 8; ++e) Ez[e] = ex2(az[e]);                        \
        _Pragma("unroll")                                                      \
        for (int e = 0; e < 8; ++e) tr[e] = ex2(ar[e]);                        \
        _Pragma("unroll")                                                      \
        for (int e = 0; e < 8; ++e) rr[e] = rcpf(1.0f + tr[e]);                \
        _Pragma("unroll")                                                      \
        for (int e = 0; e < 8; ++e) vv[e] = fmaf(rr[e], ag[e], ah[e]);         \
        _Pragma("unroll")                                                      \
        for (int e = 0; e < 8; ++e) Dv[e] = 1.0f + ex2(vv[e]);                 \
        _Pragma("unroll")                                                      \
        for (int e = 0; e < 8; ++e) num[e] = fmaf(hc[e], Dv[e],                \
                                                  (Dv[e] - 2.0f) * Ez[e]);     \
        _Pragma("unroll")                                                      \
        for (int e = 0; e < 8; ++e) den[e] = fmaf(Dv[e], Ez[e], Dv[e]);        \
        _Pragma("unroll")                                                      \
        for (int e = 0; e < 8; ++e) rd[e] = rcpf(den[e]);                      \
        _Pragma("unroll")                                                      \
        for (int e = 0; e < 8; ++e) hc[e] = num[e] * rd[e];                    \
        /* repack B-frag for next step (lane-local; THE recurrence chain) */   \
        hB.u[0] = pk_bf16(hc[1], hc[0]);                                       \
        hB.u[1] = pk_bf16(hc[3], hc[2]);                                       \
        hB.u[2] = pk_bf16(hc[5], hc[4]);                                       \
        hB.u[3] = pk_bf16(hc[7], hc[6]);                                       \
        /* dense output (OFF-chain: feeds nothing in the recurrence) */        \
        float s = fmaf(hc[0], dwA[0], hc[1] * dwA[1])                          \
                + fmaf(hc[2], dwA[2], hc[3] * dwA[3]);                         \
        s += fmaf(hc[4], dwB[0], hc[5] * dwB[1])                               \
           + fmaf(hc[6], dwB[2], hc[7] * dwB[3]);                              \
        s += SWZ16(s);                                                         \
        s += __int_as_float(BPERM(bpa, __float_as_int(s)));                    \
        if (lane < 16) obuf[(T_) * O_STRIDE + lane] = s + dbs;                 \
        pv = 0.0f;   /* delta only applies at step 0 */                        \
    } while (0)

    for (int t = 0; t < T_STEPS; t += 2) {
        GRU_STEP(t,     pa0, pb0);
        GRU_STEP(t + 1, pa1, pb1);
    }
#undef GRU_STEP

    // ---- flush outputs (single wave): coalesced dwordx4 ----
    __builtin_amdgcn_s_waitcnt(0xC07F);            // drain obuf ds_writes
    {
        const int row = lane >> 2;                 // 0..15
        const int tb  = (lane & 3) * 12;           // 0,12,24,36
        float* orow = out + (size_t)(b0 + row) * T_STEPS + tb;
#pragma unroll
        for (int k = 0; k < 3; ++k) {
            f32x4 v;
#pragma unroll
            for (int e = 0; e < 4; ++e) v[e] = obuf[(tb + k * 4 + e) * O_STRIDE + row];
            *(f32x4*)(orow + k * 4) = v;
        }
    }
}

extern "C" void kernel_launch(void* const* d_in, const int* in_sizes, int n_in,
                              void* d_out, int out_size, void* d_ws, size_t ws_size,
                              hipStream_t stream) {
    const float* feat    = (const float*)d_in[0];
    const float* init_in = (const float*)d_in[1];
    const float* init_h  = (const float*)d_in[2];
    const float* Wk      = (const float*)d_in[3];
    const float* Rk      = (const float*)d_in[4];
    const float* bx      = (const float*)d_in[5];
    const float* bh      = (const float*)d_in[6];
    const float* dw      = (const float*)d_in[7];
    const float* db      = (const float*)d_in[8];
    float* out           = (float*)d_out;

    const int B = in_sizes[2] / H_DIM;      // 32768
    dim3 grid((unsigned)(B / 16));          // one 1-wave block per 16 batch rows
    dim3 block(64);
    hipLaunchKernelGGL(gru_mfma14, grid, block, 0, stream,
                       feat, init_in, init_h, Wk, Rk, bx, bh, dw, db, out);
}